// Round 3
// baseline (147.800 us; speedup 1.0000x reference)
//
#include <hip/hip_runtime.h>

typedef __bf16 bf16x8 __attribute__((ext_vector_type(8)));
typedef __bf16 bf16x4 __attribute__((ext_vector_type(4)));
typedef float  f32x4  __attribute__((ext_vector_type(4)));

#define NGRAPH 256
#define HDIM   256
#define DDIM   128
#define ODIM   128
#define NTILES 1600          // 102400 / 64
#define EGRID  400           // enc blocks; each does NTILES/EGRID = 4 tiles

// ---------------------------------------------------------------------------
// prep: swizzle W_enc (fp32 [128][256] row-major) into MFMA B-fragment order
// (bf16), AND zero-init seg (replaces the hipMemsetAsync dispatch).
// Bsw[((kk*16+nt)*64+lane)*8 + j] = W_enc[kk*32+quad*8+j][nt*16+m]
// ---------------------------------------------------------------------------
__global__ __launch_bounds__(256) void prep_kernel(const float* __restrict__ W_enc,
                                                   __bf16* __restrict__ Bsw,
                                                   float* __restrict__ seg) {
  int tid  = blockIdx.x * 256 + threadIdx.x;   // [0, 4096)
  // zero seg: 65536 floats = 16384 float4, 4 per thread
  float4 z = {0.f, 0.f, 0.f, 0.f};
#pragma unroll
  for (int p = 0; p < 4; ++p) ((float4*)seg)[tid + p * 4096] = z;

  int lane = tid & 63;
  int t2   = tid >> 6;                          // [0, 64)
  int nt   = t2 & 15;
  int kk   = t2 >> 4;                           // [0, 4)
  int quad = lane >> 4, m = lane & 15;
  int col  = nt * 16 + m;
  bf16x8 frag;
#pragma unroll
  for (int j = 0; j < 8; ++j) {
    int k   = kk * 32 + quad * 8 + j;
    frag[j] = (__bf16)W_enc[k * HDIM + col];
  }
  *(bf16x8*)(Bsw + (size_t)tid * 8) = frag;
}

// ---------------------------------------------------------------------------
// enc v3: fused encoder + segment-sum, BARRIER-FREE.
// - Each wave loads its 16 B-fragments (its 64 output cols x full K=128) from
//   Bsw into registers ONCE, then loops over 4 row-tiles (stride EGRID).
// - A-fragments are read directly from global: lane reads rows (mt*16+m),
//   fp32 cols [kk*32+quad*8, +8) as two float4s -> cvt to bf16x8. The 4 quads
//   of one row cover one 128B cache line -> coalesced; the 4 waves of a block
//   re-read the same 32KB tile (L1/L2 absorbs; HBM traffic stays 1x).
// - No LDS, no __syncthreads: loads of tile t+1 overlap MFMA of tile t purely
//   via wave-level scheduling.
// ---------------------------------------------------------------------------
__global__ __launch_bounds__(256) void enc_kernel(const float* __restrict__ x,
                                                  const int* __restrict__ batch,
                                                  const __bf16* __restrict__ Bsw,
                                                  const float* __restrict__ b_enc,
                                                  float* __restrict__ seg) {
  const int t    = threadIdx.x;
  const int lane = t & 63, wave = t >> 6;
  const int m = lane & 15, quad = lane >> 4;

  // resident B fragments: [kk][ntl], 64 VGPRs
  bf16x8 bfr[4][4];
#pragma unroll
  for (int kk = 0; kk < 4; ++kk)
#pragma unroll
    for (int ntl = 0; ntl < 4; ++ntl)
      bfr[kk][ntl] =
          *(const bf16x8*)(Bsw + (size_t)(((kk * 16 + wave * 4 + ntl) * 64) + lane) * 8);

  // resident per-lane biases for this wave's 4 col-tiles
  float bias[4];
#pragma unroll
  for (int ntl = 0; ntl < 4; ++ntl) bias[ntl] = b_enc[(wave * 4 + ntl) * 16 + m];

  for (int tile = blockIdx.x; tile < NTILES; tile += EGRID) {
    const size_t base = (size_t)tile * 64;
    const int g0 = batch[base], g63 = batch[base + 63];

    f32x4 acc[4][4];   // [ntl][mt]
#pragma unroll
    for (int a = 0; a < 4; ++a)
#pragma unroll
      for (int b = 0; b < 4; ++b) acc[a][b] = (f32x4){0.f, 0.f, 0.f, 0.f};

#pragma unroll
    for (int kk = 0; kk < 4; ++kk) {
      bf16x8 afr[4];
#pragma unroll
      for (int mt = 0; mt < 4; ++mt) {
        const float* src = x + (base + mt * 16 + m) * DDIM + kk * 32 + quad * 8;
        float4 lo = *(const float4*)src;
        float4 hi = *(const float4*)(src + 4);
        bf16x8 a;
        a[0] = (__bf16)lo.x; a[1] = (__bf16)lo.y; a[2] = (__bf16)lo.z; a[3] = (__bf16)lo.w;
        a[4] = (__bf16)hi.x; a[5] = (__bf16)hi.y; a[6] = (__bf16)hi.z; a[7] = (__bf16)hi.w;
        afr[mt] = a;
      }
#pragma unroll
      for (int ntl = 0; ntl < 4; ++ntl)
#pragma unroll
        for (int mt = 0; mt < 4; ++mt)
          acc[ntl][mt] = __builtin_amdgcn_mfma_f32_16x16x32_bf16(
              afr[mt], bfr[kk][ntl], acc[ntl][mt], 0, 0, 0);
    }

    // epilogue: relu + bias, segment-reduce the 64 rows (block-uniform branch)
    if (g0 == g63) {
#pragma unroll
      for (int ntl = 0; ntl < 4; ++ntl) {
        float s = 0.f;
#pragma unroll
        for (int mt = 0; mt < 4; ++mt)
#pragma unroll
          for (int r = 0; r < 4; ++r)
            s += fmaxf(acc[ntl][mt][r] + bias[ntl], 0.f);
        s += __shfl_xor(s, 16, 64);
        s += __shfl_xor(s, 32, 64);
        if (quad == 0) atomicAdd(&seg[g0 * HDIM + (wave * 4 + ntl) * 16 + m], s);
      }
    } else {
      // lane's rows in increasing order: row = mt*16 + quad*4 + r
      int gl[16];
#pragma unroll
      for (int mt = 0; mt < 4; ++mt)
#pragma unroll
        for (int r = 0; r < 4; ++r) gl[mt * 4 + r] = batch[base + mt * 16 + quad * 4 + r];
#pragma unroll
      for (int ntl = 0; ntl < 4; ++ntl) {
        const int col = (wave * 4 + ntl) * 16 + m;
        int   grun = gl[0];
        float s    = 0.f;
#pragma unroll
        for (int mt = 0; mt < 4; ++mt)
#pragma unroll
          for (int r = 0; r < 4; ++r) {
            int   g = gl[mt * 4 + r];
            float v = fmaxf(acc[ntl][mt][r] + bias[ntl], 0.f);
            if (g != grun) {
              atomicAdd(&seg[grun * HDIM + col], s);
              grun = g; s = v;
            } else {
              s += v;
            }
          }
        atomicAdd(&seg[grun * HDIM + col], s);
      }
    }
  }
}

// ---------------------------------------------------------------------------
// Tail MLP v3: one graph per block, 512 threads = 8 waves (2 waves/SIMD for
// latency hiding). Per 256-wide layer: wave w owns k-chunk [w*32,+32); thread
// (w, jq) accumulates cols [4jq,4jq+4) with float4 weight loads. Partials
// reduced through LDS. Final layer: 16 k-chunks x 32 col-quads.
// ---------------------------------------------------------------------------
__device__ __forceinline__ void mlp_layer256(const float* __restrict__ buf_in,
                                             float* __restrict__ buf_out,
                                             float* __restrict__ part,  // [8][256]
                                             const float* __restrict__ W,
                                             const float* __restrict__ bias,
                                             bool relu, int t) {
  const int w  = t >> 6;          // [0,8) k-chunk
  const int jq = t & 63;          // column quad
  f32x4 acc = {0.f, 0.f, 0.f, 0.f};
  const float4* wrow = (const float4*)(W + (size_t)w * 32 * HDIM) + jq;
#pragma unroll 8
  for (int k = 0; k < 32; ++k) {
    float  a = buf_in[w * 32 + k];          // wave-uniform LDS broadcast
    float4 ww = wrow[(size_t)k * (HDIM / 4)];
    acc[0] += a * ww.x; acc[1] += a * ww.y;
    acc[2] += a * ww.z; acc[3] += a * ww.w;
  }
  *(f32x4*)&part[w * HDIM + jq * 4] = acc;
  __syncthreads();
  if (t < HDIM) {
    float v = 0.f;
#pragma unroll
    for (int r = 0; r < 8; ++r) v += part[r * HDIM + t];
    v += bias[t];
    if (relu) v = fmaxf(v, 0.f);
    buf_out[t] = v;
  }
  __syncthreads();
}

__global__ __launch_bounds__(512) void mlp_kernel(
    const float* __restrict__ seg,
    const float* __restrict__ Wv1, const float* __restrict__ bv1,
    const float* __restrict__ Wv2, const float* __restrict__ bv2,
    const float* __restrict__ Wp1, const float* __restrict__ bp1,
    const float* __restrict__ Wp2, const float* __restrict__ bp2,
    float* __restrict__ out) {
  __shared__ __align__(16) float bufA[HDIM];
  __shared__ __align__(16) float bufB[HDIM];
  __shared__ __align__(16) float part[8 * HDIM];  // viewed as [16][128] in L4
  const int t = threadIdx.x;
  const int g = blockIdx.x;

  if (t < HDIM) bufA[t] = seg[g * HDIM + t] * 0.125f;
  __syncthreads();

  mlp_layer256(bufA, bufB, part, Wv1, bv1, true,  t);
  mlp_layer256(bufB, bufA, part, Wv2, bv2, false, t);
  mlp_layer256(bufA, bufB, part, Wp1, bp1, true,  t);

  // layer 4: out[g] = bufB @ Wp2 + bp2, O=128. 16 k-chunks x 32 col-quads.
  {
    const int w  = t >> 5;        // [0,16)
    const int jq = t & 31;        // [0,32)
    f32x4 acc = {0.f, 0.f, 0.f, 0.f};
    const float4* wrow = (const float4*)(Wp2 + (size_t)w * 16 * ODIM) + jq;
#pragma unroll 8
    for (int k = 0; k < 16; ++k) {
      float  a = bufB[w * 16 + k];
      float4 ww = wrow[(size_t)k * (ODIM / 4)];
      acc[0] += a * ww.x; acc[1] += a * ww.y;
      acc[2] += a * ww.z; acc[3] += a * ww.w;
    }
    *(f32x4*)&part[w * ODIM + jq * 4] = acc;
    __syncthreads();
    if (t < ODIM) {
      float v = bp2[t];
#pragma unroll
      for (int r = 0; r < 16; ++r) v += part[r * ODIM + t];
      out[g * ODIM + t] = v;
    }
  }
}

// ---------------------------------------------------------------------------
extern "C" void kernel_launch(void* const* d_in, const int* in_sizes, int n_in,
                              void* d_out, int out_size, void* d_ws, size_t ws_size,
                              hipStream_t stream) {
  const float* x     = (const float*)d_in[0];
  // d_in[1] = edge_index : unused by the reference
  const int*   batch = (const int*)d_in[2];
  const float* W_enc = (const float*)d_in[3];
  const float* b_enc = (const float*)d_in[4];
  const float* W_v1  = (const float*)d_in[5];
  const float* b_v1  = (const float*)d_in[6];
  const float* W_v2  = (const float*)d_in[7];
  const float* b_v2  = (const float*)d_in[8];
  const float* W_p1  = (const float*)d_in[9];
  const float* b_p1  = (const float*)d_in[10];
  const float* W_p2  = (const float*)d_in[11];
  const float* b_p2  = (const float*)d_in[12];
  float* out = (float*)d_out;

  float*  seg = (float*)d_ws;                        // 256*256*4 = 262144 B
  __bf16* Bsw = (__bf16*)((char*)d_ws + 262144);     // 128*256*2 =  65536 B

  prep_kernel<<<16, 256, 0, stream>>>(W_enc, Bsw, seg);
  enc_kernel<<<EGRID, 256, 0, stream>>>(x, batch, Bsw, b_enc, seg);
  mlp_kernel<<<NGRAPH, 512, 0, stream>>>(seg, W_v1, b_v1, W_v2, b_v2,
                                         W_p1, b_p1, W_p2, b_p2, out);
}